// Round 1
// baseline (128.906 us; speedup 1.0000x reference)
//
#include <hip/hip_runtime.h>

#define BB 4
#define TT 1024
#define DD 1024
#define UU 64
#define HW 32   // WIDTH/2

// tanh via hw exp2: tanh(|x|) = (1 - e^{-2|x|}) / (1 + e^{-2|x|}), no overflow, ~1e-6 abs err
__device__ __forceinline__ float tanh_fast(float x) {
  float ax = __builtin_fabsf(x);
  float t = __expf(-2.0f * ax);                     // (0, 1]
  float r = (1.0f - t) * __builtin_amdgcn_rcpf(1.0f + t);
  return __builtin_copysignf(r, x);
}

// ---------------------------------------------------------------------------
// proj: q[row][u] = sum_d x[row][d] * Wt[d][u]; k likewise with Wx.
// grid 512 x 256. Block handles 8 contiguous rows of flattened x [4096,1024].
// Thread: u-pair (2*u2, 2*u2+1), sel (Wt/Wx), K-quarter kq. LDS tree-reduce.
// ---------------------------------------------------------------------------
__global__ __launch_bounds__(256) void proj_kernel(
    const float* __restrict__ x, const float* __restrict__ Wt,
    const float* __restrict__ Wx, float* __restrict__ qo, float* __restrict__ ko)
{
  __shared__ __align__(16) float xs[8 * DD];     // 32 KB
  __shared__ __align__(16) float red[4][1024];   // 16 KB

  const int tid  = threadIdx.x;
  const int row0 = blockIdx.x * 8;

  {
    const float4* src = (const float4*)(x + (size_t)row0 * DD);
    float4* dst = (float4*)xs;
    #pragma unroll
    for (int i = 0; i < 8; ++i) dst[tid + 256 * i] = src[tid + 256 * i];
  }
  __syncthreads();

  const int u2  = tid & 31;          // u pair = {2*u2, 2*u2+1}
  const int sel = (tid >> 5) & 1;    // 0 -> Wt/q, 1 -> Wx/k
  const int kq  = tid >> 6;          // K quarter 0..3
  const float* __restrict__ W = sel ? Wx : Wt;
  const float* __restrict__ Wp = W + 2 * u2;

  float acc0[8], acc1[8];
  #pragma unroll
  for (int r = 0; r < 8; ++r) { acc0[r] = 0.f; acc1[r] = 0.f; }

  const int dbeg = kq * 256;
  for (int dc = dbeg; dc < dbeg + 256; dc += 4) {
    float2 w0 = *(const float2*)(Wp + (size_t)(dc + 0) * UU);
    float2 w1 = *(const float2*)(Wp + (size_t)(dc + 1) * UU);
    float2 w2 = *(const float2*)(Wp + (size_t)(dc + 2) * UU);
    float2 w3 = *(const float2*)(Wp + (size_t)(dc + 3) * UU);
    #pragma unroll
    for (int r = 0; r < 8; ++r) {
      float4 xv = *(const float4*)(xs + r * DD + dc);
      acc0[r] += xv.x * w0.x + xv.y * w1.x + xv.z * w2.x + xv.w * w3.x;
      acc1[r] += xv.x * w0.y + xv.y * w1.y + xv.z * w2.y + xv.w * w3.y;
    }
  }

  // red[kq][(sel*16 + r*2 + uo)*32 + u2]  -> lanes write stride-1, conflict-free
  {
    #pragma unroll
    for (int r = 0; r < 8; ++r) {
      red[kq][(sel * 16 + r * 2 + 0) * 32 + u2] = acc0[r];
      red[kq][(sel * 16 + r * 2 + 1) * 32 + u2] = acc1[r];
    }
  }
  __syncthreads();

  #pragma unroll
  for (int m = 0; m < 4; ++m) {
    int oi = tid + 256 * m;
    float v = red[0][oi] + red[1][oi] + red[2][oi] + red[3][oi];
    int u2o  = oi & 31;
    int rest = oi >> 5;          // = sel*16 + r*2 + uo
    int uo   = rest & 1;
    int ro   = (rest >> 1) & 7;
    int so   = rest >> 4;
    float* dst = so ? ko : qo;
    dst[(size_t)(row0 + ro) * UU + 2 * u2o + uo] = v;
  }
}

// ---------------------------------------------------------------------------
// band: per block, 8 query rows (i0..i0+7) of batch b; NJ<=71 key rows.
// Stage q(+bh), k tile in LDS; scores with 8-lane u-chunk groups; softmax;
// then per-thread float4 d-slice accumulates all 8 rows over j.
// ---------------------------------------------------------------------------
__global__ __launch_bounds__(256) void band_kernel(
    const float* __restrict__ x,  const float* __restrict__ qi,
    const float* __restrict__ ki, const float* __restrict__ bh,
    const float* __restrict__ Wa, const float* __restrict__ ba,
    float* __restrict__ out)
{
  __shared__ __align__(16) float qpb[8 * UU];    // q + bh
  __shared__ __align__(16) float ks[72 * UU];    // 18 KB
  __shared__ __align__(16) float at[72 * 8];     // scores / weights, [j][i]

  const int tid  = threadIdx.x;
  const int bid  = blockIdx.x;
  const int tile = (bid & 7) * 64 + (bid >> 3);  // XCD-locality swizzle (512 = 8*64)
  const int b    = tile >> 7;
  const int i0   = (tile & 127) * 8;

  const int jlo = max(0, i0 - HW);
  const int jhi = min(TT, i0 + 8 - 1 + HW);      // exclusive; last i = i0+7, j < i+32
  const int NJ  = jhi - jlo;                     // 39..71

  // ---- stage ----
  {
    if (tid < 128) {
      float4 qv = ((const float4*)(qi + (size_t)(b * TT + i0) * UU))[tid];
      float4 bv = ((const float4*)bh)[tid & 15];
      qv.x += bv.x; qv.y += bv.y; qv.z += bv.z; qv.w += bv.w;
      ((float4*)qpb)[tid] = qv;
    }
    const float4* ksrc = (const float4*)(ki + (size_t)(b * TT + jlo) * UU);
    float4* kdst = (float4*)ks;
    const int nk4 = NJ * (UU / 4);
    for (int i2 = tid; i2 < nk4; i2 += 256) kdst[i2] = ksrc[i2];
  }
  __syncthreads();

  const float bav = ba[0];

  // ---- stage 1: scores e[i][j] ----
  {
    const int w    = tid >> 6;          // wave id: j-stride 4
    const int lane = tid & 63;
    const int g    = lane >> 3;         // i = i0 + g
    const int uc   = (lane & 7) * 8;    // 8-u chunk per lane
    float qv[8], wv[8];
    #pragma unroll
    for (int s = 0; s < 8; ++s) qv[s] = qpb[g * UU + uc + s];
    {
      float4 wa0 = *(const float4*)(Wa + uc);
      float4 wa1 = *(const float4*)(Wa + uc + 4);
      wv[0] = wa0.x; wv[1] = wa0.y; wv[2] = wa0.z; wv[3] = wa0.w;
      wv[4] = wa1.x; wv[5] = wa1.y; wv[6] = wa1.z; wv[7] = wa1.w;
    }
    const int ig = i0 + g;
    for (int j = w; j < NJ; j += 4) {
      const float* kp = ks + j * UU + uc;
      float s0 = 0.f;
      #pragma unroll
      for (int s = 0; s < 8; ++s) {
        float z = qv[s] + kp[s];
        s0 += tanh_fast(z) * wv[s];
      }
      s0 += __shfl_xor(s0, 1);
      s0 += __shfl_xor(s0, 2);
      s0 += __shfl_xor(s0, 4);
      const int jg = jlo + j;
      const bool inband = (jg >= ig - HW) && (jg < ig + HW);
      if ((lane & 7) == 0) at[j * 8 + g] = inband ? (s0 + bav) : -1e30f;
    }
  }
  __syncthreads();

  // ---- stage 2: softmax per row over j ----
  {
    const int row = tid >> 5;   // 0..7
    const int l   = tid & 31;
    float v0 = (l      < NJ) ? at[(l     ) * 8 + row] : -1e30f;
    float v1 = (l + 32 < NJ) ? at[(l + 32) * 8 + row] : -1e30f;
    float v2 = (l + 64 < NJ) ? at[(l + 64) * 8 + row] : -1e30f;
    float m = fmaxf(fmaxf(v0, v1), v2);
    #pragma unroll
    for (int off = 16; off >= 1; off >>= 1) m = fmaxf(m, __shfl_xor(m, off, 32));
    float e0 = __expf(v0 - m);
    float e1 = __expf(v1 - m);
    float e2 = __expf(v2 - m);
    float ssum = e0 + e1 + e2;
    #pragma unroll
    for (int off = 16; off >= 1; off >>= 1) ssum += __shfl_xor(ssum, off, 32);
    float inv = 1.0f / ssum;
    if (l      < NJ) at[(l     ) * 8 + row] = e0 * inv;
    if (l + 32 < NJ) at[(l + 32) * 8 + row] = e1 * inv;
    if (l + 64 < NJ) at[(l + 64) * 8 + row] = e2 * inv;
  }
  __syncthreads();

  // ---- stage 3: v = a @ x ----
  {
    float4 vacc[8];
    #pragma unroll
    for (int i = 0; i < 8; ++i) vacc[i] = make_float4(0.f, 0.f, 0.f, 0.f);
    const float* xb = x + (size_t)(b * TT + jlo) * DD + 4 * tid;
    for (int j = 0; j < NJ; ++j) {
      float4 xv = *(const float4*)(xb + (size_t)j * DD);
      float4 a0 = *(const float4*)(at + j * 8);
      float4 a1 = *(const float4*)(at + j * 8 + 4);
      float av[8] = {a0.x, a0.y, a0.z, a0.w, a1.x, a1.y, a1.z, a1.w};
      #pragma unroll
      for (int i = 0; i < 8; ++i) {
        vacc[i].x = __builtin_fmaf(av[i], xv.x, vacc[i].x);
        vacc[i].y = __builtin_fmaf(av[i], xv.y, vacc[i].y);
        vacc[i].z = __builtin_fmaf(av[i], xv.z, vacc[i].z);
        vacc[i].w = __builtin_fmaf(av[i], xv.w, vacc[i].w);
      }
    }
    float* ob = out + (size_t)(b * TT + i0) * DD + 4 * tid;
    #pragma unroll
    for (int i = 0; i < 8; ++i) *(float4*)(ob + (size_t)i * DD) = vacc[i];
  }
}

// ---------------------------------------------------------------------------
extern "C" void kernel_launch(void* const* d_in, const int* in_sizes, int n_in,
                              void* d_out, int out_size, void* d_ws, size_t ws_size,
                              hipStream_t stream) {
  const float* x  = (const float*)d_in[0];
  const float* Wt = (const float*)d_in[1];
  const float* Wx = (const float*)d_in[2];
  const float* bh = (const float*)d_in[3];
  const float* Wa = (const float*)d_in[4];
  const float* ba = (const float*)d_in[5];
  float* out = (float*)d_out;

  float* q = (float*)d_ws;                       // [4096, 64]
  float* k = q + (size_t)BB * TT * UU;           // [4096, 64]  (2 MB total)

  proj_kernel<<<dim3((BB * TT) / 8), dim3(256), 0, stream>>>(x, Wt, Wx, q, k);
  band_kernel<<<dim3((BB * TT) / 8), dim3(256), 0, stream>>>(x, q, k, bh, Wa, ba, out);
}

// Round 2
// 122.271 us; speedup vs baseline: 1.0543x; 1.0543x over previous
//
#include <hip/hip_runtime.h>

#define BB 4
#define TT 1024
#define DD 1024
#define UU 64
#define HW 32   // WIDTH/2

// tanh via hw exp: tanh(|x|) = (1 - e^{-2|x|}) / (1 + e^{-2|x|}), no overflow, ~1e-6 abs err
__device__ __forceinline__ float tanh_fast(float x) {
  float ax = __builtin_fabsf(x);
  float t = __expf(-2.0f * ax);                     // (0, 1]
  float r = (1.0f - t) * __builtin_amdgcn_rcpf(1.0f + t);
  return __builtin_copysignf(r, x);
}

// ---------------------------------------------------------------------------
// proj: q[row][u] = sum_d x[row][d]*Wt[d][u]; k likewise with Wx.
// grid 512 x 512 threads. Block = 8 rows. Thread = u-pair(32) x sel(2) x kq(8).
// Each W element read exactly once per block; 8-partial LDS reduce.
// 4 waves/SIMD for latency hiding.
// ---------------------------------------------------------------------------
__global__ __launch_bounds__(512) void proj_kernel(
    const float* __restrict__ x, const float* __restrict__ Wt,
    const float* __restrict__ Wx, float* __restrict__ qo, float* __restrict__ ko)
{
  __shared__ __align__(16) float xs[8 * DD];     // 32 KB
  __shared__ __align__(16) float red[8][1024];   // 32 KB  [kq][out]

  const int tid  = threadIdx.x;
  const int row0 = blockIdx.x * 8;

  {
    const float4* src = (const float4*)(x + (size_t)row0 * DD);
    float4* dst = (float4*)xs;
    #pragma unroll
    for (int i = 0; i < 4; ++i) dst[tid + 512 * i] = src[tid + 512 * i];
  }
  __syncthreads();

  const int u2  = tid & 31;          // u pair {2*u2, 2*u2+1}
  const int sel = (tid >> 5) & 1;    // 0 -> Wt/q, 1 -> Wx/k
  const int kq  = tid >> 6;          // K eighth 0..7 (128 d each)
  const float* __restrict__ W = sel ? Wx : Wt;
  const float* __restrict__ Wp = W + 2 * u2;

  float acc0[8], acc1[8];
  #pragma unroll
  for (int r = 0; r < 8; ++r) { acc0[r] = 0.f; acc1[r] = 0.f; }

  const int dbeg = kq * 128;
  #pragma unroll 4
  for (int dc = dbeg; dc < dbeg + 128; dc += 4) {
    float2 w0 = *(const float2*)(Wp + (size_t)(dc + 0) * UU);
    float2 w1 = *(const float2*)(Wp + (size_t)(dc + 1) * UU);
    float2 w2 = *(const float2*)(Wp + (size_t)(dc + 2) * UU);
    float2 w3 = *(const float2*)(Wp + (size_t)(dc + 3) * UU);
    #pragma unroll
    for (int r = 0; r < 8; ++r) {
      float4 xv = *(const float4*)(xs + r * DD + dc);
      acc0[r] += xv.x * w0.x + xv.y * w1.x + xv.z * w2.x + xv.w * w3.x;
      acc1[r] += xv.x * w0.y + xv.y * w1.y + xv.z * w2.y + xv.w * w3.y;
    }
  }

  // out index oi = (sel*8 + r)*64 + 2*u2 + uo ; float2 write is conflict-free
  {
    #pragma unroll
    for (int r = 0; r < 8; ++r) {
      *(float2*)(&red[kq][(sel * 8 + r) * 64 + 2 * u2]) = make_float2(acc0[r], acc1[r]);
    }
  }
  __syncthreads();

  #pragma unroll
  for (int m = 0; m < 2; ++m) {
    int oi = tid + 512 * m;
    float v = 0.f;
    #pragma unroll
    for (int p = 0; p < 8; ++p) v += red[p][oi];
    int c  = oi & 63;
    int r  = (oi >> 6) & 7;
    int so = oi >> 9;
    float* dst = so ? ko : qo;
    dst[(size_t)(row0 + r) * UU + c] = v;
  }
}

// ---------------------------------------------------------------------------
// band: per block, 8 query rows (i0..i0+7) of batch b; NJ<=71 key rows.
// 512 threads (8 waves): scores (8-lane u-chunks, j-stride 8), softmax
// (one wave per row), then per-thread float2 d-slice over all 8 rows.
// ---------------------------------------------------------------------------
__global__ __launch_bounds__(512) void band_kernel(
    const float* __restrict__ x,  const float* __restrict__ qi,
    const float* __restrict__ ki, const float* __restrict__ bh,
    const float* __restrict__ Wa, const float* __restrict__ ba,
    float* __restrict__ out)
{
  __shared__ __align__(16) float qpb[8 * UU];    // q + bh
  __shared__ __align__(16) float ks[72 * UU];    // 18 KB
  __shared__ __align__(16) float at[72 * 8];     // scores / weights, [j][i]

  const int tid  = threadIdx.x;
  const int bid  = blockIdx.x;
  const int tile = (bid & 7) * 64 + (bid >> 3);  // XCD-locality swizzle (512 = 8*64)
  const int b    = tile >> 7;
  const int i0   = (tile & 127) * 8;

  const int jlo = max(0, i0 - HW);
  const int jhi = min(TT, i0 + 8 - 1 + HW);      // exclusive
  const int NJ  = jhi - jlo;                     // 39..71

  // ---- stage q(+bh), k ----
  {
    if (tid < 128) {
      float4 qv = ((const float4*)(qi + (size_t)(b * TT + i0) * UU))[tid];
      float4 bv = ((const float4*)bh)[tid & 15];
      qv.x += bv.x; qv.y += bv.y; qv.z += bv.z; qv.w += bv.w;
      ((float4*)qpb)[tid] = qv;
    }
    const float4* ksrc = (const float4*)(ki + (size_t)(b * TT + jlo) * UU);
    float4* kdst = (float4*)ks;
    const int nk4 = NJ * (UU / 4);
    for (int i2 = tid; i2 < nk4; i2 += 512) kdst[i2] = ksrc[i2];
  }
  __syncthreads();

  const float bav = ba[0];

  // ---- stage 1: scores e[i][j] ----
  {
    const int w    = tid >> 6;          // wave id: j-stride 8
    const int lane = tid & 63;
    const int g    = lane >> 3;         // i = i0 + g
    const int uc   = (lane & 7) * 8;    // 8-u chunk per lane
    float qv[8], wv[8];
    #pragma unroll
    for (int s = 0; s < 8; ++s) qv[s] = qpb[g * UU + uc + s];
    {
      float4 wa0 = *(const float4*)(Wa + uc);
      float4 wa1 = *(const float4*)(Wa + uc + 4);
      wv[0] = wa0.x; wv[1] = wa0.y; wv[2] = wa0.z; wv[3] = wa0.w;
      wv[4] = wa1.x; wv[5] = wa1.y; wv[6] = wa1.z; wv[7] = wa1.w;
    }
    const int ig = i0 + g;
    for (int j = w; j < NJ; j += 8) {
      const float* kp = ks + j * UU + uc;
      float s0 = 0.f;
      #pragma unroll
      for (int s = 0; s < 8; ++s) {
        float z = qv[s] + kp[s];
        s0 += tanh_fast(z) * wv[s];
      }
      s0 += __shfl_xor(s0, 1);
      s0 += __shfl_xor(s0, 2);
      s0 += __shfl_xor(s0, 4);
      const int jg = jlo + j;
      const bool inband = (jg >= ig - HW) && (jg < ig + HW);
      if ((lane & 7) == 0) at[j * 8 + g] = inband ? (s0 + bav) : -1e30f;
    }
  }
  __syncthreads();

  // ---- stage 2: softmax per row over j (one wave per row) ----
  {
    const int row = tid >> 6;   // 0..7
    const int l   = tid & 63;
    float v0 = (l      < NJ) ? at[(l     ) * 8 + row] : -1e30f;
    float v1 = (l + 64 < NJ) ? at[(l + 64) * 8 + row] : -1e30f;
    float m = fmaxf(v0, v1);
    #pragma unroll
    for (int off = 32; off >= 1; off >>= 1) m = fmaxf(m, __shfl_xor(m, off));
    float e0 = __expf(v0 - m);
    float e1 = __expf(v1 - m);
    float ssum = e0 + e1;
    #pragma unroll
    for (int off = 32; off >= 1; off >>= 1) ssum += __shfl_xor(ssum, off);
    float inv = 1.0f / ssum;
    if (l      < NJ) at[(l     ) * 8 + row] = e0 * inv;
    if (l + 64 < NJ) at[(l + 64) * 8 + row] = e1 * inv;
  }
  __syncthreads();

  // ---- stage 3: v = a @ x  (thread owns float2 d-slice, all 8 rows) ----
  {
    float2 vacc[8];
    #pragma unroll
    for (int i = 0; i < 8; ++i) vacc[i] = make_float2(0.f, 0.f);
    const float* xb = x + (size_t)(b * TT + jlo) * DD + 2 * tid;
    #pragma unroll 2
    for (int j = 0; j < NJ; ++j) {
      float2 xv = *(const float2*)(xb + (size_t)j * DD);
      float4 a0 = *(const float4*)(at + j * 8);
      float4 a1 = *(const float4*)(at + j * 8 + 4);
      float av[8] = {a0.x, a0.y, a0.z, a0.w, a1.x, a1.y, a1.z, a1.w};
      #pragma unroll
      for (int i = 0; i < 8; ++i) {
        vacc[i].x = __builtin_fmaf(av[i], xv.x, vacc[i].x);
        vacc[i].y = __builtin_fmaf(av[i], xv.y, vacc[i].y);
      }
    }
    float* ob = out + (size_t)(b * TT + i0) * DD + 2 * tid;
    #pragma unroll
    for (int i = 0; i < 8; ++i) *(float2*)(ob + (size_t)i * DD) = vacc[i];
  }
}

// ---------------------------------------------------------------------------
extern "C" void kernel_launch(void* const* d_in, const int* in_sizes, int n_in,
                              void* d_out, int out_size, void* d_ws, size_t ws_size,
                              hipStream_t stream) {
  const float* x  = (const float*)d_in[0];
  const float* Wt = (const float*)d_in[1];
  const float* Wx = (const float*)d_in[2];
  const float* bh = (const float*)d_in[3];
  const float* Wa = (const float*)d_in[4];
  const float* ba = (const float*)d_in[5];
  float* out = (float*)d_out;

  float* q = (float*)d_ws;                       // [4096, 64]
  float* k = q + (size_t)BB * TT * UU;           // [4096, 64]  (2 MB total)

  proj_kernel<<<dim3((BB * TT) / 8), dim3(512), 0, stream>>>(x, Wt, Wx, q, k);
  band_kernel<<<dim3((BB * TT) / 8), dim3(512), 0, stream>>>(x, q, k, bh, Wa, ba, out);
}